// Round 6
// baseline (459.027 us; speedup 1.0000x reference)
//
#include <hip/hip_runtime.h>
#include <hip/hip_bf16.h>

#define SEQ 4096
#define NB 2
#define DM 512
#define NH 8
#define DK 64

typedef __bf16 bf16;
typedef __bf16 bf16x4 __attribute__((ext_vector_type(4)));
typedef __bf16 bf16x8 __attribute__((ext_vector_type(8)));
typedef float  f32x4 __attribute__((ext_vector_type(4)));

__device__ __forceinline__ f32x4 mfma16(bf16x8 a, bf16x8 b, f32x4 c) {
    return __builtin_amdgcn_mfma_f32_16x16x32_bf16(a, b, c, 0, 0, 0);
}

__device__ __forceinline__ float fexp2(float x) {
    return __builtin_amdgcn_exp2f(x);   // raw v_exp_f32 (2^x)
}

// Async global->LDS, 16B per lane. LDS dest is wave-uniform base + lane*16.
__device__ __forceinline__ void gload_lds16(const bf16* g, bf16* l) {
    __builtin_amdgcn_global_load_lds(
        (const __attribute__((address_space(1))) void*)g,
        (__attribute__((address_space(3))) void*)l, 16, 0, 0);
}

// LDS rows are 64 bf16 (128 B). XOR-swizzle 16B slot by row (G4 fix).
__device__ __forceinline__ int swzE(int row, int e) {
    return row * 64 + (e ^ ((row & 7) << 3));
}

__device__ __forceinline__ void split2(float f, bf16& h, bf16& l) {
    bf16 hh = (bf16)f;
    h = hh;
    l = (bf16)(f - (float)hh);
}

// Load 8 contiguous fp32, scale, split into hi/lo bf16x8.
__device__ __forceinline__ void split8(const float* __restrict__ p, float scale,
                                       bf16x8& h, bf16x8& l) {
    const float4 v0 = *(const float4*)p;
    const float4 v1 = *(const float4*)(p + 4);
    float f0 = v0.x * scale, f1 = v0.y * scale, f2 = v0.z * scale, f3 = v0.w * scale;
    float f4 = v1.x * scale, f5 = v1.y * scale, f6 = v1.z * scale, f7 = v1.w * scale;
    bf16 h0 = (bf16)f0, h1 = (bf16)f1, h2 = (bf16)f2, h3 = (bf16)f3;
    bf16 h4 = (bf16)f4, h5 = (bf16)f5, h6 = (bf16)f6, h7 = (bf16)f7;
    h = (bf16x8){h0, h1, h2, h3, h4, h5, h6, h7};
    l = (bf16x8){(bf16)(f0 - (float)h0), (bf16)(f1 - (float)h1),
                 (bf16)(f2 - (float)h2), (bf16)(f3 - (float)h3),
                 (bf16)(f4 - (float)h4), (bf16)(f5 - (float)h5),
                 (bf16)(f6 - (float)h6), (bf16)(f7 - (float)h7)};
}

// ---------------------------------------------------------------------------
// Transpose + split weights: W[K][N] fp32 -> Wt_hi/lo[N][K] bf16.
// ---------------------------------------------------------------------------
__global__ __launch_bounds__(256)
void prep_w(const float* __restrict__ W, bf16* __restrict__ Wth,
            bf16* __restrict__ Wtl, int K, int N) {
    __shared__ float T[64][65];
    const int k0 = blockIdx.x * 64, n0 = blockIdx.y * 64;
    const int t = threadIdx.x;
    #pragma unroll
    for (int i = 0; i < 4; ++i) {
        int r = i * 16 + (t >> 4);
        int c = (t & 15) * 4;
        float4 v = *(const float4*)&W[(size_t)(k0 + r) * N + n0 + c];
        T[r][c + 0] = v.x; T[r][c + 1] = v.y; T[r][c + 2] = v.z; T[r][c + 3] = v.w;
    }
    __syncthreads();
    #pragma unroll
    for (int i = 0; i < 4; ++i) {
        int n = i * 16 + (t >> 4);
        int c = (t & 15) * 4;
        float a0 = T[c + 0][n], a1 = T[c + 1][n], a2 = T[c + 2][n], a3 = T[c + 3][n];
        bf16 h0 = (bf16)a0, h1 = (bf16)a1, h2 = (bf16)a2, h3 = (bf16)a3;
        bf16x4 hv = (bf16x4){h0, h1, h2, h3};
        bf16x4 lv = (bf16x4){(bf16)(a0 - (float)h0), (bf16)(a1 - (float)h1),
                             (bf16)(a2 - (float)h2), (bf16)(a3 - (float)h3)};
        *(bf16x4*)&Wth[(size_t)(n0 + n) * K + k0 + c] = hv;
        *(bf16x4*)&Wtl[(size_t)(n0 + n) * K + k0 + c] = lv;
    }
}

// ---------------------------------------------------------------------------
// Split-bf16 MFMA GEMM: C[M,N] fp32 = A[M,K] fp32 @ Bt[N,K]^T (pre-split bf16).
// 128x128 tile, BK=64, 4 waves of 64x64 (4x4 16x16x32 frags), 3-term split.
// ---------------------------------------------------------------------------
__global__ __launch_bounds__(256, 2)
void gemm_split(const float* __restrict__ A, const bf16* __restrict__ Bth,
                const bf16* __restrict__ Btl, float* __restrict__ C,
                int M, int N, int K) {
    __shared__ bf16 Ah[128 * 64], Al[128 * 64], Bh[128 * 64], Bl[128 * 64];
    const int t = threadIdx.x;
    const int lane = t & 63, w = t >> 6;
    const int l15 = lane & 15, g = lane >> 4;
    const int wm = (w >> 1) * 64, wn = (w & 1) * 64;
    const int rowA = blockIdx.y * 128;
    const int colB = blockIdx.x * 128;
    const int sr = t >> 1;          // staging row 0..127
    const int sc = (t & 1) * 32;    // staging k-chunk

    f32x4 acc[4][4] = {};

    for (int k0 = 0; k0 < K; k0 += 64) {
        __syncthreads();
        #pragma unroll
        for (int u = 0; u < 4; ++u) {   // A: fp32 -> hi/lo
            bf16x8 h, l;
            split8(&A[(size_t)(rowA + sr) * K + k0 + sc + u * 8], 1.0f, h, l);
            int off = swzE(sr, sc + u * 8);
            *(bf16x8*)&Ah[off] = h;
            *(bf16x8*)&Al[off] = l;
        }
        #pragma unroll
        for (int u = 0; u < 4; ++u) {   // B: pre-split copy
            int off = swzE(sr, sc + u * 8);
            *(bf16x8*)&Bh[off] = *(const bf16x8*)&Bth[(size_t)(colB + sr) * K + k0 + sc + u * 8];
            *(bf16x8*)&Bl[off] = *(const bf16x8*)&Btl[(size_t)(colB + sr) * K + k0 + sc + u * 8];
        }
        __syncthreads();
        #pragma unroll
        for (int kst = 0; kst < 2; ++kst) {
            bf16x8 ah[4], al[4];
            #pragma unroll
            for (int mi = 0; mi < 4; ++mi) {
                int off = swzE(wm + mi * 16 + l15, kst * 32 + g * 8);
                ah[mi] = *(const bf16x8*)&Ah[off];
                al[mi] = *(const bf16x8*)&Al[off];
            }
            #pragma unroll
            for (int ni = 0; ni < 4; ++ni) {
                int off = swzE(wn + ni * 16 + l15, kst * 32 + g * 8);
                bf16x8 bh = *(const bf16x8*)&Bh[off];
                bf16x8 bl = *(const bf16x8*)&Bl[off];
                #pragma unroll
                for (int mi = 0; mi < 4; ++mi) {
                    acc[mi][ni] = mfma16(ah[mi], bh, acc[mi][ni]);
                    acc[mi][ni] = mfma16(ah[mi], bl, acc[mi][ni]);
                    acc[mi][ni] = mfma16(al[mi], bh, acc[mi][ni]);
                }
            }
        }
    }
    #pragma unroll
    for (int mi = 0; mi < 4; ++mi)
        #pragma unroll
        for (int ni = 0; ni < 4; ++ni)
            #pragma unroll
            for (int r = 0; r < 4; ++r) {
                int row = rowA + wm + mi * 16 + g * 4 + r;
                int col = colB + wn + ni * 16 + l15;
                C[(size_t)row * N + col] = acc[mi][ni][r];
            }
}

// ---------------------------------------------------------------------------
// Convert K,V from fp32 qkv to split bf16. K: [bh][s][d] hi/lo. V: transposed
// AND slot-permuted [bh][d][slot], slot = (s&15)*4 + ((s>>4)&3) within each
// 64-block — the same permutation the flash kernel uses for P, so PV is exact.
// ---------------------------------------------------------------------------
__global__ __launch_bounds__(256)
void convert_kv(const float* __restrict__ qkv,
                bf16* __restrict__ Kh, bf16* __restrict__ Kl,
                bf16* __restrict__ Vth, bf16* __restrict__ Vtl) {
    const int st = blockIdx.x, h = blockIdx.y, b = blockIdx.z;
    const int bh = b * NH + h;
    __shared__ float VT[64][68];
    const int t = threadIdx.x;
    const int r = t >> 2, c16 = (t & 3) * 16;

    // K rows
    const size_t kbase = ((size_t)(b * SEQ + st * 64 + r) * 3 + 1) * DM + h * DK;
    #pragma unroll
    for (int u = 0; u < 2; ++u) {
        bf16x8 hh, ll;
        split8(&qkv[kbase + c16 + u * 8], 1.0f, hh, ll);
        size_t o = ((size_t)bh * SEQ + st * 64 + r) * DK + c16 + u * 8;
        *(bf16x8*)&Kh[o] = hh;
        *(bf16x8*)&Kl[o] = ll;
    }
    // V -> LDS fp32
    const size_t vbase = ((size_t)(b * SEQ + st * 64 + r) * 3 + 2) * DM + h * DK;
    #pragma unroll
    for (int u = 0; u < 4; ++u) {
        float4 v = *(const float4*)&qkv[vbase + c16 + u * 4];
        VT[r][c16 + u * 4 + 0] = v.x; VT[r][c16 + u * 4 + 1] = v.y;
        VT[r][c16 + u * 4 + 2] = v.z; VT[r][c16 + u * 4 + 3] = v.w;
    }
    __syncthreads();
    // transposed + permuted write: thread owns d=r, slots c16..c16+15
    bf16x8 vh0{}, vh1{}, vl0{}, vl1{};
    #pragma unroll
    for (int i = 0; i < 8; ++i) {
        int slot = c16 + i;
        float f = VT[(slot & 3) * 16 + (slot >> 2)][r];
        bf16 hh = (bf16)f;
        vh0[i] = hh; vl0[i] = (bf16)(f - (float)hh);
    }
    #pragma unroll
    for (int i = 0; i < 8; ++i) {
        int slot = c16 + 8 + i;
        float f = VT[(slot & 3) * 16 + (slot >> 2)][r];
        bf16 hh = (bf16)f;
        vh1[i] = hh; vl1[i] = (bf16)(f - (float)hh);
    }
    size_t vo = ((size_t)bh * DK + r) * SEQ + st * 64 + c16;
    *(bf16x8*)&Vth[vo] = vh0;     *(bf16x8*)&Vth[vo + 8] = vh1;
    *(bf16x8*)&Vtl[vo] = vl0;     *(bf16x8*)&Vtl[vo + 8] = vl1;
}

// ---------------------------------------------------------------------------
// MFMA flash attention. Block = 128 q-rows of one (b,h); 8 waves x 16 q-rows.
// K/V tile = 64 staged via global_load_lds (width 16, linear LDS dest,
// pre-swizzled global source column — G21 both-sides rule). No reg prefetch,
// no launch_bounds occupancy clamp (R5's VGPR=64 clamp caused 24 MB of spill
// traffic). exp2-domain softmax with defer-max.
// ---------------------------------------------------------------------------
__global__ __launch_bounds__(512)
void flash_mfma(const float* __restrict__ qkv,
                const bf16* __restrict__ Kh, const bf16* __restrict__ Kl,
                const bf16* __restrict__ Vth, const bf16* __restrict__ Vtl,
                float* __restrict__ att) {
    // XCD-bijective swizzle: nwg = 512 (divisible by 8).
    const int nwg = (int)gridDim.x;
    const int cpx = nwg >> 3;
    const int bid = (int)blockIdx.x;
    const int wg = (bid & 7) * cpx + (bid >> 3);
    const int qt = wg & 31;
    const int bh = wg >> 5;
    const int h = bh & 7, b = bh >> 3;

    __shared__ bf16 KhS[64 * 64], KlS[64 * 64], VhS[64 * 64], VlS[64 * 64]; // 32 KB
    __shared__ bf16 PhS[128 * 64], PlS[128 * 64];                           // 32 KB

    const int t = threadIdx.x, lane = t & 63, w = t >> 6;   // 8 waves
    const int l15 = lane & 15, g = lane >> 4;
    const int q0 = qt * 128;
    const int wq = w * 16;   // each wave owns 16 q-rows

    const float LOG2E = 1.44269504088896f;

    // Q fragments in registers (scaled by log2e/8, split hi/lo)
    bf16x8 qh[2], ql[2];
    {
        const int row = q0 + wq + l15;
        const size_t base = ((size_t)(b * SEQ + row) * 3 + 0) * DM + h * DK + g * 8;
        split8(&qkv[base], 0.125f * LOG2E, qh[0], ql[0]);
        split8(&qkv[base + 32], 0.125f * LOG2E, qh[1], ql[1]);
    }

    float m_run[4], l_run[4];
    f32x4 o[4] = {};
    #pragma unroll
    for (int r = 0; r < 4; ++r) { m_run[r] = -1e30f; l_run[r] = 0.f; }

    // staging geometry: thread t covers row sr = t>>3, 16B slot sc8 = (t&7)*8.
    // LDS linear dest byte = sr*128 + sc8*2 = w*1024 + lane*16 (wave-uniform
    // base + lane*16 — exactly global_load_lds's fixed pattern). Global source
    // column pre-swizzled so that swzE() reads see the right data.
    const int sr = t >> 3;
    const int sc8 = (t & 7) * 8;
    const int scs = sc8 ^ ((sr & 7) << 3);     // pre-swizzled column
    const size_t kgo = ((size_t)bh * SEQ + sr) * DK + scs;
    const size_t vgo = ((size_t)bh * DK + sr) * SEQ + scs;
    bf16* ldsKh = KhS + w * 512;   // 1024 B per wave
    bf16* ldsKl = KlS + w * 512;
    bf16* ldsVh = VhS + w * 512;
    bf16* ldsVl = VlS + w * 512;

    const int NT = SEQ / 64;
    for (int kt = 0; kt < NT; ++kt) {
        __syncthreads();   // all waves done reading previous tile's LDS
        {
            const size_t ko = kgo + (size_t)kt * 64 * DK;
            const size_t vo = vgo + (size_t)kt * 64;
            gload_lds16(Kh + ko, ldsKh);
            gload_lds16(Kl + ko, ldsKl);
            gload_lds16(Vth + vo, ldsVh);
            gload_lds16(Vtl + vo, ldsVl);
        }
        __syncthreads();   // vmcnt(0) drain -> tile visible

        // ---- scores: 3-term split MFMA ----
        f32x4 s[4] = {};
        #pragma unroll
        for (int kst = 0; kst < 2; ++kst) {
            #pragma unroll
            for (int ni = 0; ni < 4; ++ni) {
                int off = swzE(ni * 16 + l15, kst * 32 + g * 8);
                bf16x8 kh_ = *(const bf16x8*)&KhS[off];
                bf16x8 kl_ = *(const bf16x8*)&KlS[off];
                s[ni] = mfma16(qh[kst], kh_, s[ni]);
                s[ni] = mfma16(ql[kst], kh_, s[ni]);
                s[ni] = mfma16(qh[kst], kl_, s[ni]);
            }
        }

        // ---- online softmax (exp2 domain) with defer-max ----
        #pragma unroll
        for (int r = 0; r < 4; ++r) {
            float mx = fmaxf(fmaxf(s[0][r], s[1][r]), fmaxf(s[2][r], s[3][r]));
            #pragma unroll
            for (int off = 1; off < 16; off <<= 1)
                mx = fmaxf(mx, __shfl_xor(mx, off));
            if (__any(mx - m_run[r] > 8.0f)) {
                const float mnew  = fmaxf(m_run[r], mx);
                const float alpha = fexp2(m_run[r] - mnew);
                #pragma unroll
                for (int ni = 0; ni < 4; ++ni) o[ni][r] *= alpha;
                l_run[r] *= alpha;
                m_run[r] = mnew;
            }
            float p0 = fexp2(s[0][r] - m_run[r]);
            float p1 = fexp2(s[1][r] - m_run[r]);
            float p2 = fexp2(s[2][r] - m_run[r]);
            float p3 = fexp2(s[3][r] - m_run[r]);
            float rs = (p0 + p1) + (p2 + p3);
            #pragma unroll
            for (int off = 1; off < 16; off <<= 1)
                rs += __shfl_xor(rs, off);
            l_run[r] += rs;

            bf16 h0, l0, h1, l1, h2, l2, h3, l3;
            split2(p0, h0, l0); split2(p1, h1, l1);
            split2(p2, h2, l2); split2(p3, h3, l3);
            const int prow = wq + g * 4 + r;
            const int e = swzE(prow, l15 * 4);
            *(bf16x4*)&PhS[e] = (bf16x4){h0, h1, h2, h3};
            *(bf16x4*)&PlS[e] = (bf16x4){l0, l1, l2, l3};
        }
        // P rows are wave-private: no barrier needed.

        // ---- O += P @ V (3-term split) ----
        #pragma unroll
        for (int kst = 0; kst < 2; ++kst) {
            const int poff = swzE(wq + l15, kst * 32 + g * 8);
            bf16x8 ph = *(const bf16x8*)&PhS[poff];
            bf16x8 pl = *(const bf16x8*)&PlS[poff];
            #pragma unroll
            for (int ni = 0; ni < 4; ++ni) {
                int off = swzE(ni * 16 + l15, kst * 32 + g * 8);
                bf16x8 vh_ = *(const bf16x8*)&VhS[off];
                bf16x8 vl_ = *(const bf16x8*)&VlS[off];
                o[ni] = mfma16(ph, vh_, o[ni]);
                o[ni] = mfma16(pl, vh_, o[ni]);
                o[ni] = mfma16(ph, vl_, o[ni]);
            }
        }
    }

    // ---- epilogue ----
    #pragma unroll
    for (int r = 0; r < 4; ++r) {
        const float inv = 1.0f / l_run[r];
        const int row = q0 + wq + g * 4 + r;
        #pragma unroll
        for (int ni = 0; ni < 4; ++ni)
            att[(size_t)(b * SEQ + row) * DM + h * DK + ni * 16 + l15] =
                o[ni][r] * inv;
    }
}

// ---------------------------------------------------------------------------
extern "C" void kernel_launch(void* const* d_in, const int* in_sizes, int n_in,
                              void* d_out, int out_size, void* d_ws, size_t ws_size,
                              hipStream_t stream) {
    const float* x    = (const float*)d_in[0];
    const float* Wqkv = (const float*)d_in[1];
    const float* Wout = (const float*)d_in[2];
    float* out = (float*)d_out;

    char* ws = (char*)d_ws;
    float* qkv  = (float*)(ws);                          // 48 MB
    float* attn = (float*)(ws + (size_t)48 * 1048576);   // 16 MB
    bf16* Khp  = (bf16*)(ws + (size_t)64 * 1048576);     // 8 MB
    bf16* Klp  = (bf16*)(ws + (size_t)72 * 1048576);     // 8 MB
    bf16* Vthp = (bf16*)(ws + (size_t)80 * 1048576);     // 8 MB
    bf16* Vtlp = (bf16*)(ws + (size_t)88 * 1048576);     // 8 MB
    bf16* Wqh  = (bf16*)(ws + (size_t)96 * 1048576);     // 1.5 MB
    bf16* Wql  = (bf16*)(ws + (size_t)98 * 1048576);
    bf16* Woh  = (bf16*)(ws + (size_t)100 * 1048576);    // 0.5 MB
    bf16* Wol  = (bf16*)(ws + (size_t)101 * 1048576);

    const int M = NB * SEQ;   // 8192

    prep_w<<<dim3(DM / 64, (3 * DM) / 64), 256, 0, stream>>>(Wqkv, Wqh, Wql, DM, 3 * DM);
    prep_w<<<dim3(DM / 64, DM / 64), 256, 0, stream>>>(Wout, Woh, Wol, DM, DM);

    gemm_split<<<dim3((3 * DM) / 128, M / 128), 256, 0, stream>>>(
        x, Wqh, Wql, qkv, M, 3 * DM, DM);

    convert_kv<<<dim3(SEQ / 64, NH, NB), 256, 0, stream>>>(qkv, Khp, Klp, Vthp, Vtlp);

    flash_mfma<<<dim3((SEQ / 128) * NH * NB), 512, 0, stream>>>(
        qkv, Khp, Klp, Vthp, Vtlp, attn);

    gemm_split<<<dim3(DM / 128, M / 128), 256, 0, stream>>>(
        attn, Woh, Wol, out, M, DM, DM);
}

// Round 7
// 352.063 us; speedup vs baseline: 1.3038x; 1.3038x over previous
//
#include <hip/hip_runtime.h>
#include <hip/hip_bf16.h>

#define SEQ 4096
#define NB 2
#define DM 512
#define NH 8
#define DK 64

typedef __bf16 bf16;
typedef __bf16 bf16x4 __attribute__((ext_vector_type(4)));
typedef __bf16 bf16x8 __attribute__((ext_vector_type(8)));
typedef float  f32x4 __attribute__((ext_vector_type(4)));

__device__ __forceinline__ f32x4 mfma16(bf16x8 a, bf16x8 b, f32x4 c) {
    return __builtin_amdgcn_mfma_f32_16x16x32_bf16(a, b, c, 0, 0, 0);
}

__device__ __forceinline__ float fexp2(float x) {
    return __builtin_amdgcn_exp2f(x);   // raw v_exp_f32 (2^x)
}

// Async global->LDS, 16B per lane. LDS dest is wave-uniform base + lane*16.
__device__ __forceinline__ void gload_lds16(const bf16* g, bf16* l) {
    __builtin_amdgcn_global_load_lds(
        (const __attribute__((address_space(1))) void*)g,
        (__attribute__((address_space(3))) void*)l, 16, 0, 0);
}

// LDS rows are 64 bf16 (128 B). XOR-swizzle 16B slot by row (G4 fix).
__device__ __forceinline__ int swzE(int row, int e) {
    return row * 64 + (e ^ ((row & 7) << 3));
}

__device__ __forceinline__ void split2(float f, bf16& h, bf16& l) {
    bf16 hh = (bf16)f;
    h = hh;
    l = (bf16)(f - (float)hh);
}

// Load 8 contiguous fp32, scale, split into hi/lo bf16x8.
__device__ __forceinline__ void split8(const float* __restrict__ p, float scale,
                                       bf16x8& h, bf16x8& l) {
    const float4 v0 = *(const float4*)p;
    const float4 v1 = *(const float4*)(p + 4);
    float f0 = v0.x * scale, f1 = v0.y * scale, f2 = v0.z * scale, f3 = v0.w * scale;
    float f4 = v1.x * scale, f5 = v1.y * scale, f6 = v1.z * scale, f7 = v1.w * scale;
    bf16 h0 = (bf16)f0, h1 = (bf16)f1, h2 = (bf16)f2, h3 = (bf16)f3;
    bf16 h4 = (bf16)f4, h5 = (bf16)f5, h6 = (bf16)f6, h7 = (bf16)f7;
    h = (bf16x8){h0, h1, h2, h3, h4, h5, h6, h7};
    l = (bf16x8){(bf16)(f0 - (float)h0), (bf16)(f1 - (float)h1),
                 (bf16)(f2 - (float)h2), (bf16)(f3 - (float)h3),
                 (bf16)(f4 - (float)h4), (bf16)(f5 - (float)h5),
                 (bf16)(f6 - (float)h6), (bf16)(f7 - (float)h7)};
}

// ---------------------------------------------------------------------------
// Transpose + split weights: W[K][N] fp32 -> Wt_hi/lo[N][K] bf16.
// ---------------------------------------------------------------------------
__global__ __launch_bounds__(256)
void prep_w(const float* __restrict__ W, bf16* __restrict__ Wth,
            bf16* __restrict__ Wtl, int K, int N) {
    __shared__ float T[64][65];
    const int k0 = blockIdx.x * 64, n0 = blockIdx.y * 64;
    const int t = threadIdx.x;
    #pragma unroll
    for (int i = 0; i < 4; ++i) {
        int r = i * 16 + (t >> 4);
        int c = (t & 15) * 4;
        float4 v = *(const float4*)&W[(size_t)(k0 + r) * N + n0 + c];
        T[r][c + 0] = v.x; T[r][c + 1] = v.y; T[r][c + 2] = v.z; T[r][c + 3] = v.w;
    }
    __syncthreads();
    #pragma unroll
    for (int i = 0; i < 4; ++i) {
        int n = i * 16 + (t >> 4);
        int c = (t & 15) * 4;
        float a0 = T[c + 0][n], a1 = T[c + 1][n], a2 = T[c + 2][n], a3 = T[c + 3][n];
        bf16 h0 = (bf16)a0, h1 = (bf16)a1, h2 = (bf16)a2, h3 = (bf16)a3;
        bf16x4 hv = (bf16x4){h0, h1, h2, h3};
        bf16x4 lv = (bf16x4){(bf16)(a0 - (float)h0), (bf16)(a1 - (float)h1),
                             (bf16)(a2 - (float)h2), (bf16)(a3 - (float)h3)};
        *(bf16x4*)&Wth[(size_t)(n0 + n) * K + k0 + c] = hv;
        *(bf16x4*)&Wtl[(size_t)(n0 + n) * K + k0 + c] = lv;
    }
}

// ---------------------------------------------------------------------------
// Split-bf16 MFMA GEMM: C[M,N] fp32 = A[M,K] fp32 @ Bt[N,K]^T (pre-split bf16).
// 128x128 tile, BK=64, 4 waves of 64x64 (4x4 16x16x32 frags), 3-term split.
// ---------------------------------------------------------------------------
__global__ __launch_bounds__(256, 2)
void gemm_split(const float* __restrict__ A, const bf16* __restrict__ Bth,
                const bf16* __restrict__ Btl, float* __restrict__ C,
                int M, int N, int K) {
    __shared__ bf16 Ah[128 * 64], Al[128 * 64], Bh[128 * 64], Bl[128 * 64];
    const int t = threadIdx.x;
    const int lane = t & 63, w = t >> 6;
    const int l15 = lane & 15, g = lane >> 4;
    const int wm = (w >> 1) * 64, wn = (w & 1) * 64;
    const int rowA = blockIdx.y * 128;
    const int colB = blockIdx.x * 128;
    const int sr = t >> 1;          // staging row 0..127
    const int sc = (t & 1) * 32;    // staging k-chunk

    f32x4 acc[4][4] = {};

    for (int k0 = 0; k0 < K; k0 += 64) {
        __syncthreads();
        #pragma unroll
        for (int u = 0; u < 4; ++u) {   // A: fp32 -> hi/lo
            bf16x8 h, l;
            split8(&A[(size_t)(rowA + sr) * K + k0 + sc + u * 8], 1.0f, h, l);
            int off = swzE(sr, sc + u * 8);
            *(bf16x8*)&Ah[off] = h;
            *(bf16x8*)&Al[off] = l;
        }
        #pragma unroll
        for (int u = 0; u < 4; ++u) {   // B: pre-split copy
            int off = swzE(sr, sc + u * 8);
            *(bf16x8*)&Bh[off] = *(const bf16x8*)&Bth[(size_t)(colB + sr) * K + k0 + sc + u * 8];
            *(bf16x8*)&Bl[off] = *(const bf16x8*)&Btl[(size_t)(colB + sr) * K + k0 + sc + u * 8];
        }
        __syncthreads();
        #pragma unroll
        for (int kst = 0; kst < 2; ++kst) {
            bf16x8 ah[4], al[4];
            #pragma unroll
            for (int mi = 0; mi < 4; ++mi) {
                int off = swzE(wm + mi * 16 + l15, kst * 32 + g * 8);
                ah[mi] = *(const bf16x8*)&Ah[off];
                al[mi] = *(const bf16x8*)&Al[off];
            }
            #pragma unroll
            for (int ni = 0; ni < 4; ++ni) {
                int off = swzE(wn + ni * 16 + l15, kst * 32 + g * 8);
                bf16x8 bh = *(const bf16x8*)&Bh[off];
                bf16x8 bl = *(const bf16x8*)&Bl[off];
                #pragma unroll
                for (int mi = 0; mi < 4; ++mi) {
                    acc[mi][ni] = mfma16(ah[mi], bh, acc[mi][ni]);
                    acc[mi][ni] = mfma16(ah[mi], bl, acc[mi][ni]);
                    acc[mi][ni] = mfma16(al[mi], bh, acc[mi][ni]);
                }
            }
        }
    }
    #pragma unroll
    for (int mi = 0; mi < 4; ++mi)
        #pragma unroll
        for (int ni = 0; ni < 4; ++ni)
            #pragma unroll
            for (int r = 0; r < 4; ++r) {
                int row = rowA + wm + mi * 16 + g * 4 + r;
                int col = colB + wn + ni * 16 + l15;
                C[(size_t)row * N + col] = acc[mi][ni][r];
            }
}

// ---------------------------------------------------------------------------
// Convert K,V from fp32 qkv to split bf16. K: [bh][s][d] hi/lo. V: transposed
// AND slot-permuted [bh][d][slot], slot = (s&15)*4 + ((s>>4)&3) within each
// 64-block — the same permutation the flash kernel uses for P, so PV is exact.
// ---------------------------------------------------------------------------
__global__ __launch_bounds__(256)
void convert_kv(const float* __restrict__ qkv,
                bf16* __restrict__ Kh, bf16* __restrict__ Kl,
                bf16* __restrict__ Vth, bf16* __restrict__ Vtl) {
    const int st = blockIdx.x, h = blockIdx.y, b = blockIdx.z;
    const int bh = b * NH + h;
    __shared__ float VT[64][68];
    const int t = threadIdx.x;
    const int r = t >> 2, c16 = (t & 3) * 16;

    // K rows
    const size_t kbase = ((size_t)(b * SEQ + st * 64 + r) * 3 + 1) * DM + h * DK;
    #pragma unroll
    for (int u = 0; u < 2; ++u) {
        bf16x8 hh, ll;
        split8(&qkv[kbase + c16 + u * 8], 1.0f, hh, ll);
        size_t o = ((size_t)bh * SEQ + st * 64 + r) * DK + c16 + u * 8;
        *(bf16x8*)&Kh[o] = hh;
        *(bf16x8*)&Kl[o] = ll;
    }
    // V -> LDS fp32
    const size_t vbase = ((size_t)(b * SEQ + st * 64 + r) * 3 + 2) * DM + h * DK;
    #pragma unroll
    for (int u = 0; u < 4; ++u) {
        float4 v = *(const float4*)&qkv[vbase + c16 + u * 4];
        VT[r][c16 + u * 4 + 0] = v.x; VT[r][c16 + u * 4 + 1] = v.y;
        VT[r][c16 + u * 4 + 2] = v.z; VT[r][c16 + u * 4 + 3] = v.w;
    }
    __syncthreads();
    // transposed + permuted write: thread owns d=r, slots c16..c16+15
    bf16x8 vh0{}, vh1{}, vl0{}, vl1{};
    #pragma unroll
    for (int i = 0; i < 8; ++i) {
        int slot = c16 + i;
        float f = VT[(slot & 3) * 16 + (slot >> 2)][r];
        bf16 hh = (bf16)f;
        vh0[i] = hh; vl0[i] = (bf16)(f - (float)hh);
    }
    #pragma unroll
    for (int i = 0; i < 8; ++i) {
        int slot = c16 + 8 + i;
        float f = VT[(slot & 3) * 16 + (slot >> 2)][r];
        bf16 hh = (bf16)f;
        vh1[i] = hh; vl1[i] = (bf16)(f - (float)hh);
    }
    size_t vo = ((size_t)bh * DK + r) * SEQ + st * 64 + c16;
    *(bf16x8*)&Vth[vo] = vh0;     *(bf16x8*)&Vth[vo + 8] = vh1;
    *(bf16x8*)&Vtl[vo] = vl0;     *(bf16x8*)&Vtl[vo + 8] = vl1;
}

// ---------------------------------------------------------------------------
// MFMA flash attention, R7: 2-phase double-buffered pipeline (T3 minimum).
// Block = 256 q-rows of one (b,h); 8 waves x 32 q-rows. K/V tile = 64.
// stage(t+1) issued at loop top via global_load_lds into the other buffer;
// ONE __syncthreads() per iteration at the bottom (its vmcnt(0) drain lands
// AFTER the compute phase -> load latency hidden; also fences buffer reuse).
// 128 KB dynamic LDS (K/V hi+lo dbuf 64K + P hi/lo 64K) -> 1 block/CU.
// ---------------------------------------------------------------------------
__global__ __launch_bounds__(512)
void flash_mfma(const float* __restrict__ qkv,
                const bf16* __restrict__ Kh, const bf16* __restrict__ Kl,
                const bf16* __restrict__ Vth, const bf16* __restrict__ Vtl,
                float* __restrict__ att) {
    extern __shared__ bf16 smem[];
    bf16* KhS = smem;              // [2][64*64]
    bf16* KlS = smem + 8192;
    bf16* VhS = smem + 16384;
    bf16* VlS = smem + 24576;
    bf16* PhS = smem + 32768;      // [256*64]
    bf16* PlS = smem + 49152;

    // XCD-bijective swizzle: nwg = 256 (divisible by 8).
    const int nwg = (int)gridDim.x;
    const int cpx = nwg >> 3;
    const int bid = (int)blockIdx.x;
    const int wg = (bid & 7) * cpx + (bid >> 3);
    const int qt = wg & 15;        // 16 q-tiles of 256 rows
    const int bh = wg >> 4;
    const int h = bh & 7, b = bh >> 3;

    const int t = threadIdx.x, lane = t & 63, w = t >> 6;   // 8 waves
    const int l15 = lane & 15, g = lane >> 4;
    const int q0 = qt * 256;
    const int wq = w * 32;   // each wave owns 32 q-rows

    const float LOG2E = 1.44269504088896f;

    // Q fragments in registers (scaled by log2e/8, split hi/lo)
    bf16x8 qh[2][2], ql[2][2];
    #pragma unroll
    for (int mi = 0; mi < 2; ++mi) {
        const int row = q0 + wq + mi * 16 + l15;
        const size_t base = ((size_t)(b * SEQ + row) * 3 + 0) * DM + h * DK + g * 8;
        #pragma unroll
        for (int kst = 0; kst < 2; ++kst)
            split8(&qkv[base + kst * 32], 0.125f * LOG2E, qh[mi][kst], ql[mi][kst]);
    }

    float m_run[2][4], l_run[2][4];
    f32x4 o[2][4] = {};
    #pragma unroll
    for (int mi = 0; mi < 2; ++mi)
        #pragma unroll
        for (int r = 0; r < 4; ++r) { m_run[mi][r] = -1e30f; l_run[mi][r] = 0.f; }

    // Staging geometry: thread t covers linear element t*8 of the 64x64 tile
    // (row sr=t>>3, col sc8=(t&7)*8); LDS dest = wave-uniform base + lane*16B,
    // exactly global_load_lds's pattern. Global source column pre-swizzled
    // (G21 both-sides rule) so swzE() reads see the right data.
    const int sr = t >> 3;
    const int sc8 = (t & 7) * 8;
    const int scs = sc8 ^ ((sr & 7) << 3);
    const size_t kgo = ((size_t)bh * SEQ + sr) * DK + scs;
    const size_t vgo = ((size_t)bh * DK + sr) * SEQ + scs;
    const int dst = t * 8;   // element offset within a [64*64] buffer

    auto stage = [&](int kt, int c) {
        const size_t ko = kgo + (size_t)kt * 64 * DK;
        const size_t vo = vgo + (size_t)kt * 64;
        const int cb = c * 4096 + dst;
        gload_lds16(Kh + ko,  KhS + cb);
        gload_lds16(Kl + ko,  KlS + cb);
        gload_lds16(Vth + vo, VhS + cb);
        gload_lds16(Vtl + vo, VlS + cb);
    };

    const int NT = SEQ / 64;
    stage(0, 0);
    __syncthreads();   // drain tile-0 DMA

    for (int kt = 0; kt < NT; ++kt) {
        const int c = kt & 1;
        if (kt + 1 < NT) stage(kt + 1, c ^ 1);   // async loads overlap compute
        const int cb = c * 4096;

        // ---- scores: 3-term split MFMA ----
        f32x4 s[2][4] = {};
        #pragma unroll
        for (int kst = 0; kst < 2; ++kst) {
            #pragma unroll
            for (int ni = 0; ni < 4; ++ni) {
                int off = cb + swzE(ni * 16 + l15, kst * 32 + g * 8);
                bf16x8 kh_ = *(const bf16x8*)&KhS[off];
                bf16x8 kl_ = *(const bf16x8*)&KlS[off];
                #pragma unroll
                for (int mi = 0; mi < 2; ++mi) {
                    s[mi][ni] = mfma16(qh[mi][kst], kh_, s[mi][ni]);
                    s[mi][ni] = mfma16(ql[mi][kst], kh_, s[mi][ni]);
                    s[mi][ni] = mfma16(qh[mi][kst], kl_, s[mi][ni]);
                }
            }
        }

        // ---- online softmax (exp2 domain) with defer-max ----
        #pragma unroll
        for (int mi = 0; mi < 2; ++mi) {
            #pragma unroll
            for (int r = 0; r < 4; ++r) {
                float mx = fmaxf(fmaxf(s[mi][0][r], s[mi][1][r]),
                                 fmaxf(s[mi][2][r], s[mi][3][r]));
                #pragma unroll
                for (int off = 1; off < 16; off <<= 1)
                    mx = fmaxf(mx, __shfl_xor(mx, off));
                if (__any(mx - m_run[mi][r] > 8.0f)) {
                    const float mnew  = fmaxf(m_run[mi][r], mx);
                    const float alpha = fexp2(m_run[mi][r] - mnew);
                    #pragma unroll
                    for (int ni = 0; ni < 4; ++ni) o[mi][ni][r] *= alpha;
                    l_run[mi][r] *= alpha;
                    m_run[mi][r] = mnew;
                }
                float p0 = fexp2(s[mi][0][r] - m_run[mi][r]);
                float p1 = fexp2(s[mi][1][r] - m_run[mi][r]);
                float p2 = fexp2(s[mi][2][r] - m_run[mi][r]);
                float p3 = fexp2(s[mi][3][r] - m_run[mi][r]);
                float rs = (p0 + p1) + (p2 + p3);
                #pragma unroll
                for (int off = 1; off < 16; off <<= 1)
                    rs += __shfl_xor(rs, off);
                l_run[mi][r] += rs;

                bf16 h0, l0, h1, l1, h2, l2, h3, l3;
                split2(p0, h0, l0); split2(p1, h1, l1);
                split2(p2, h2, l2); split2(p3, h3, l3);
                const int prow = wq + mi * 16 + g * 4 + r;
                const int e = swzE(prow, l15 * 4);
                *(bf16x4*)&PhS[e] = (bf16x4){h0, h1, h2, h3};
                *(bf16x4*)&PlS[e] = (bf16x4){l0, l1, l2, l3};
            }
        }
        // P rows are wave-private: no barrier needed.

        // ---- O += P @ V (3-term split) ----
        #pragma unroll
        for (int kst = 0; kst < 2; ++kst) {
            bf16x8 ph[2], pl[2];
            #pragma unroll
            for (int mi = 0; mi < 2; ++mi) {
                int poff = swzE(wq + mi * 16 + l15, kst * 32 + g * 8);
                ph[mi] = *(const bf16x8*)&PhS[poff];
                pl[mi] = *(const bf16x8*)&PlS[poff];
            }
            #pragma unroll
            for (int ni = 0; ni < 4; ++ni) {
                int off = cb + swzE(ni * 16 + l15, kst * 32 + g * 8);
                bf16x8 vh_ = *(const bf16x8*)&VhS[off];
                bf16x8 vl_ = *(const bf16x8*)&VlS[off];
                #pragma unroll
                for (int mi = 0; mi < 2; ++mi) {
                    o[mi][ni] = mfma16(ph[mi], vh_, o[mi][ni]);
                    o[mi][ni] = mfma16(pl[mi], vh_, o[mi][ni]);
                    o[mi][ni] = mfma16(ph[mi], vl_, o[mi][ni]);
                }
            }
        }

        __syncthreads();   // drains next-tile DMA; fences buffer reuse
    }

    // ---- epilogue ----
    #pragma unroll
    for (int mi = 0; mi < 2; ++mi)
        #pragma unroll
        for (int r = 0; r < 4; ++r) {
            const float inv = 1.0f / l_run[mi][r];
            const int row = q0 + wq + mi * 16 + g * 4 + r;
            #pragma unroll
            for (int ni = 0; ni < 4; ++ni)
                att[(size_t)(b * SEQ + row) * DM + h * DK + ni * 16 + l15] =
                    o[mi][ni][r] * inv;
        }
}

// ---------------------------------------------------------------------------
extern "C" void kernel_launch(void* const* d_in, const int* in_sizes, int n_in,
                              void* d_out, int out_size, void* d_ws, size_t ws_size,
                              hipStream_t stream) {
    const float* x    = (const float*)d_in[0];
    const float* Wqkv = (const float*)d_in[1];
    const float* Wout = (const float*)d_in[2];
    float* out = (float*)d_out;

    char* ws = (char*)d_ws;
    float* qkv  = (float*)(ws);                          // 48 MB
    float* attn = (float*)(ws + (size_t)48 * 1048576);   // 16 MB
    bf16* Khp  = (bf16*)(ws + (size_t)64 * 1048576);     // 8 MB
    bf16* Klp  = (bf16*)(ws + (size_t)72 * 1048576);     // 8 MB
    bf16* Vthp = (bf16*)(ws + (size_t)80 * 1048576);     // 8 MB
    bf16* Vtlp = (bf16*)(ws + (size_t)88 * 1048576);     // 8 MB
    bf16* Wqh  = (bf16*)(ws + (size_t)96 * 1048576);     // 1.5 MB
    bf16* Wql  = (bf16*)(ws + (size_t)98 * 1048576);
    bf16* Woh  = (bf16*)(ws + (size_t)100 * 1048576);    // 0.5 MB
    bf16* Wol  = (bf16*)(ws + (size_t)101 * 1048576);

    const int M = NB * SEQ;   // 8192
    const int FLASH_LDS = 131072;   // 128 KB dynamic LDS

    // Opt in to >64KB dynamic LDS (idempotent host call; not a stream op).
    hipFuncSetAttribute((const void*)flash_mfma,
                        hipFuncAttributeMaxDynamicSharedMemorySize, FLASH_LDS);

    prep_w<<<dim3(DM / 64, (3 * DM) / 64), 256, 0, stream>>>(Wqkv, Wqh, Wql, DM, 3 * DM);
    prep_w<<<dim3(DM / 64, DM / 64), 256, 0, stream>>>(Wout, Woh, Wol, DM, DM);

    gemm_split<<<dim3((3 * DM) / 128, M / 128), 256, 0, stream>>>(
        x, Wqh, Wql, qkv, M, 3 * DM, DM);

    convert_kv<<<dim3(SEQ / 64, NH, NB), 256, 0, stream>>>(qkv, Khp, Klp, Vthp, Vtlp);

    flash_mfma<<<dim3((SEQ / 256) * NH * NB), 512, FLASH_LDS, stream>>>(
        qkv, Khp, Klp, Vthp, Vtlp, attn);

    gemm_split<<<dim3(DM / 128, M / 128), 256, 0, stream>>>(
        attn, Woh, Wol, out, M, DM, DM);
}

// Round 8
// 289.359 us; speedup vs baseline: 1.5864x; 1.2167x over previous
//
#include <hip/hip_runtime.h>
#include <hip/hip_bf16.h>

#define SEQ 4096
#define NB 2
#define DM 512
#define NH 8
#define DK 64

typedef __bf16 bf16;
typedef __bf16 bf16x4 __attribute__((ext_vector_type(4)));
typedef __bf16 bf16x8 __attribute__((ext_vector_type(8)));
typedef float  f32x4 __attribute__((ext_vector_type(4)));

__device__ __forceinline__ f32x4 mfma16(bf16x8 a, bf16x8 b, f32x4 c) {
    return __builtin_amdgcn_mfma_f32_16x16x32_bf16(a, b, c, 0, 0, 0);
}

__device__ __forceinline__ float fexp2(float x) {
    return __builtin_amdgcn_exp2f(x);   // raw v_exp_f32 (2^x)
}

// Async global->LDS, 16B per lane. LDS dest is wave-uniform base + lane*16.
__device__ __forceinline__ void gload_lds16(const bf16* g, bf16* l) {
    __builtin_amdgcn_global_load_lds(
        (const __attribute__((address_space(1))) void*)g,
        (__attribute__((address_space(3))) void*)l, 16, 0, 0);
}

// LDS rows are 64 bf16 (128 B). XOR-swizzle 16B slot by row (G4 fix).
__device__ __forceinline__ int swzE(int row, int e) {
    return row * 64 + (e ^ ((row & 7) << 3));
}

__device__ __forceinline__ void split2(float f, bf16& h, bf16& l) {
    bf16 hh = (bf16)f;
    h = hh;
    l = (bf16)(f - (float)hh);
}

// Load 8 contiguous fp32, scale, split into hi/lo bf16x8.
__device__ __forceinline__ void split8(const float* __restrict__ p, float scale,
                                       bf16x8& h, bf16x8& l) {
    const float4 v0 = *(const float4*)p;
    const float4 v1 = *(const float4*)(p + 4);
    float f0 = v0.x * scale, f1 = v0.y * scale, f2 = v0.z * scale, f3 = v0.w * scale;
    float f4 = v1.x * scale, f5 = v1.y * scale, f6 = v1.z * scale, f7 = v1.w * scale;
    bf16 h0 = (bf16)f0, h1 = (bf16)f1, h2 = (bf16)f2, h3 = (bf16)f3;
    bf16 h4 = (bf16)f4, h5 = (bf16)f5, h6 = (bf16)f6, h7 = (bf16)f7;
    h = (bf16x8){h0, h1, h2, h3, h4, h5, h6, h7};
    l = (bf16x8){(bf16)(f0 - (float)h0), (bf16)(f1 - (float)h1),
                 (bf16)(f2 - (float)h2), (bf16)(f3 - (float)h3),
                 (bf16)(f4 - (float)h4), (bf16)(f5 - (float)h5),
                 (bf16)(f6 - (float)h6), (bf16)(f7 - (float)h7)};
}

// ---------------------------------------------------------------------------
// Transpose + split weights: W[K][N] fp32 -> Wt_hi/lo[N][K] bf16.
// ---------------------------------------------------------------------------
__global__ __launch_bounds__(256)
void prep_w(const float* __restrict__ W, bf16* __restrict__ Wth,
            bf16* __restrict__ Wtl, int K, int N) {
    __shared__ float T[64][65];
    const int k0 = blockIdx.x * 64, n0 = blockIdx.y * 64;
    const int t = threadIdx.x;
    #pragma unroll
    for (int i = 0; i < 4; ++i) {
        int r = i * 16 + (t >> 4);
        int c = (t & 15) * 4;
        float4 v = *(const float4*)&W[(size_t)(k0 + r) * N + n0 + c];
        T[r][c + 0] = v.x; T[r][c + 1] = v.y; T[r][c + 2] = v.z; T[r][c + 3] = v.w;
    }
    __syncthreads();
    #pragma unroll
    for (int i = 0; i < 4; ++i) {
        int n = i * 16 + (t >> 4);
        int c = (t & 15) * 4;
        float a0 = T[c + 0][n], a1 = T[c + 1][n], a2 = T[c + 2][n], a3 = T[c + 3][n];
        bf16 h0 = (bf16)a0, h1 = (bf16)a1, h2 = (bf16)a2, h3 = (bf16)a3;
        bf16x4 hv = (bf16x4){h0, h1, h2, h3};
        bf16x4 lv = (bf16x4){(bf16)(a0 - (float)h0), (bf16)(a1 - (float)h1),
                             (bf16)(a2 - (float)h2), (bf16)(a3 - (float)h3)};
        *(bf16x4*)&Wth[(size_t)(n0 + n) * K + k0 + c] = hv;
        *(bf16x4*)&Wtl[(size_t)(n0 + n) * K + k0 + c] = lv;
    }
}

// ---------------------------------------------------------------------------
// Split-bf16 MFMA GEMM: C[M,N] fp32 = A[M,K] fp32 @ Bt[N,K]^T (pre-split bf16).
// 128x128 tile, BK=64, 4 waves of 64x64 (4x4 16x16x32 frags), 3-term split.
// ---------------------------------------------------------------------------
__global__ __launch_bounds__(256, 2)
void gemm_split(const float* __restrict__ A, const bf16* __restrict__ Bth,
                const bf16* __restrict__ Btl, float* __restrict__ C,
                int M, int N, int K) {
    __shared__ bf16 Ah[128 * 64], Al[128 * 64], Bh[128 * 64], Bl[128 * 64];
    const int t = threadIdx.x;
    const int lane = t & 63, w = t >> 6;
    const int l15 = lane & 15, g = lane >> 4;
    const int wm = (w >> 1) * 64, wn = (w & 1) * 64;
    const int rowA = blockIdx.y * 128;
    const int colB = blockIdx.x * 128;
    const int sr = t >> 1;          // staging row 0..127
    const int sc = (t & 1) * 32;    // staging k-chunk

    f32x4 acc[4][4] = {};

    for (int k0 = 0; k0 < K; k0 += 64) {
        __syncthreads();
        #pragma unroll
        for (int u = 0; u < 4; ++u) {   // A: fp32 -> hi/lo
            bf16x8 h, l;
            split8(&A[(size_t)(rowA + sr) * K + k0 + sc + u * 8], 1.0f, h, l);
            int off = swzE(sr, sc + u * 8);
            *(bf16x8*)&Ah[off] = h;
            *(bf16x8*)&Al[off] = l;
        }
        #pragma unroll
        for (int u = 0; u < 4; ++u) {   // B: pre-split copy
            int off = swzE(sr, sc + u * 8);
            *(bf16x8*)&Bh[off] = *(const bf16x8*)&Bth[(size_t)(colB + sr) * K + k0 + sc + u * 8];
            *(bf16x8*)&Bl[off] = *(const bf16x8*)&Btl[(size_t)(colB + sr) * K + k0 + sc + u * 8];
        }
        __syncthreads();
        #pragma unroll
        for (int kst = 0; kst < 2; ++kst) {
            bf16x8 ah[4], al[4];
            #pragma unroll
            for (int mi = 0; mi < 4; ++mi) {
                int off = swzE(wm + mi * 16 + l15, kst * 32 + g * 8);
                ah[mi] = *(const bf16x8*)&Ah[off];
                al[mi] = *(const bf16x8*)&Al[off];
            }
            #pragma unroll
            for (int ni = 0; ni < 4; ++ni) {
                int off = swzE(wn + ni * 16 + l15, kst * 32 + g * 8);
                bf16x8 bh = *(const bf16x8*)&Bh[off];
                bf16x8 bl = *(const bf16x8*)&Bl[off];
                #pragma unroll
                for (int mi = 0; mi < 4; ++mi) {
                    acc[mi][ni] = mfma16(ah[mi], bh, acc[mi][ni]);
                    acc[mi][ni] = mfma16(ah[mi], bl, acc[mi][ni]);
                    acc[mi][ni] = mfma16(al[mi], bh, acc[mi][ni]);
                }
            }
        }
    }
    #pragma unroll
    for (int mi = 0; mi < 4; ++mi)
        #pragma unroll
        for (int ni = 0; ni < 4; ++ni)
            #pragma unroll
            for (int r = 0; r < 4; ++r) {
                int row = rowA + wm + mi * 16 + g * 4 + r;
                int col = colB + wn + ni * 16 + l15;
                C[(size_t)row * N + col] = acc[mi][ni][r];
            }
}

// ---------------------------------------------------------------------------
// Convert K,V from fp32 qkv to split bf16. K: [bh][s][d] hi/lo. V: transposed
// AND slot-permuted [bh][d][slot], slot = (s&15)*4 + ((s>>4)&3) within each
// 64-block — the same permutation the flash kernel uses for P, so PV is exact.
// ---------------------------------------------------------------------------
__global__ __launch_bounds__(256)
void convert_kv(const float* __restrict__ qkv,
                bf16* __restrict__ Kh, bf16* __restrict__ Kl,
                bf16* __restrict__ Vth, bf16* __restrict__ Vtl) {
    const int st = blockIdx.x, h = blockIdx.y, b = blockIdx.z;
    const int bh = b * NH + h;
    __shared__ float VT[64][68];
    const int t = threadIdx.x;
    const int r = t >> 2, c16 = (t & 3) * 16;

    // K rows
    const size_t kbase = ((size_t)(b * SEQ + st * 64 + r) * 3 + 1) * DM + h * DK;
    #pragma unroll
    for (int u = 0; u < 2; ++u) {
        bf16x8 hh, ll;
        split8(&qkv[kbase + c16 + u * 8], 1.0f, hh, ll);
        size_t o = ((size_t)bh * SEQ + st * 64 + r) * DK + c16 + u * 8;
        *(bf16x8*)&Kh[o] = hh;
        *(bf16x8*)&Kl[o] = ll;
    }
    // V -> LDS fp32
    const size_t vbase = ((size_t)(b * SEQ + st * 64 + r) * 3 + 2) * DM + h * DK;
    #pragma unroll
    for (int u = 0; u < 4; ++u) {
        float4 v = *(const float4*)&qkv[vbase + c16 + u * 4];
        VT[r][c16 + u * 4 + 0] = v.x; VT[r][c16 + u * 4 + 1] = v.y;
        VT[r][c16 + u * 4 + 2] = v.z; VT[r][c16 + u * 4 + 3] = v.w;
    }
    __syncthreads();
    // transposed + permuted write: thread owns d=r, slots c16..c16+15
    bf16x8 vh0{}, vh1{}, vl0{}, vl1{};
    #pragma unroll
    for (int i = 0; i < 8; ++i) {
        int slot = c16 + i;
        float f = VT[(slot & 3) * 16 + (slot >> 2)][r];
        bf16 hh = (bf16)f;
        vh0[i] = hh; vl0[i] = (bf16)(f - (float)hh);
    }
    #pragma unroll
    for (int i = 0; i < 8; ++i) {
        int slot = c16 + 8 + i;
        float f = VT[(slot & 3) * 16 + (slot >> 2)][r];
        bf16 hh = (bf16)f;
        vh1[i] = hh; vl1[i] = (bf16)(f - (float)hh);
    }
    size_t vo = ((size_t)bh * DK + r) * SEQ + st * 64 + c16;
    *(bf16x8*)&Vth[vo] = vh0;     *(bf16x8*)&Vth[vo + 8] = vh1;
    *(bf16x8*)&Vtl[vo] = vl0;     *(bf16x8*)&Vtl[vo + 8] = vl1;
}

// ---------------------------------------------------------------------------
// MFMA flash attention, R8: R7's 2-phase dbuf pipeline + softmax fast path.
// - max reduce (4x shfl) only inside the rare rescale branch (__any on
//   LOCAL max is the same boolean as on the reduced max).
// - l_run kept as per-lane partials; one 16-lane reduce in the epilogue.
// - s_setprio(1) around both MFMA clusters (T5).
// ---------------------------------------------------------------------------
__global__ __launch_bounds__(512)
void flash_mfma(const float* __restrict__ qkv,
                const bf16* __restrict__ Kh, const bf16* __restrict__ Kl,
                const bf16* __restrict__ Vth, const bf16* __restrict__ Vtl,
                float* __restrict__ att) {
    extern __shared__ bf16 smem[];
    bf16* KhS = smem;              // [2][64*64]
    bf16* KlS = smem + 8192;
    bf16* VhS = smem + 16384;
    bf16* VlS = smem + 24576;
    bf16* PhS = smem + 32768;      // [256*64]
    bf16* PlS = smem + 49152;

    // XCD-bijective swizzle: nwg = 256 (divisible by 8).
    const int nwg = (int)gridDim.x;
    const int cpx = nwg >> 3;
    const int bid = (int)blockIdx.x;
    const int wg = (bid & 7) * cpx + (bid >> 3);
    const int qt = wg & 15;        // 16 q-tiles of 256 rows
    const int bh = wg >> 4;
    const int h = bh & 7, b = bh >> 3;

    const int t = threadIdx.x, lane = t & 63, w = t >> 6;   // 8 waves
    const int l15 = lane & 15, g = lane >> 4;
    const int q0 = qt * 256;
    const int wq = w * 32;   // each wave owns 32 q-rows

    const float LOG2E = 1.44269504088896f;

    // Q fragments in registers (scaled by log2e/8, split hi/lo)
    bf16x8 qh[2][2], ql[2][2];
    #pragma unroll
    for (int mi = 0; mi < 2; ++mi) {
        const int row = q0 + wq + mi * 16 + l15;
        const size_t base = ((size_t)(b * SEQ + row) * 3 + 0) * DM + h * DK + g * 8;
        #pragma unroll
        for (int kst = 0; kst < 2; ++kst)
            split8(&qkv[base + kst * 32], 0.125f * LOG2E, qh[mi][kst], ql[mi][kst]);
    }

    float m_run[2][4], l_run[2][4];
    f32x4 o[2][4] = {};
    #pragma unroll
    for (int mi = 0; mi < 2; ++mi)
        #pragma unroll
        for (int r = 0; r < 4; ++r) { m_run[mi][r] = -1e30f; l_run[mi][r] = 0.f; }

    // Staging geometry (see R7 comment): LDS dest = wave base + lane*16B;
    // global source column pre-swizzled (G21 both-sides rule).
    const int sr = t >> 3;
    const int sc8 = (t & 7) * 8;
    const int scs = sc8 ^ ((sr & 7) << 3);
    const size_t kgo = ((size_t)bh * SEQ + sr) * DK + scs;
    const size_t vgo = ((size_t)bh * DK + sr) * SEQ + scs;
    const int dst = t * 8;   // element offset within a [64*64] buffer

    auto stage = [&](int kt, int c) {
        const size_t ko = kgo + (size_t)kt * 64 * DK;
        const size_t vo = vgo + (size_t)kt * 64;
        const int cb = c * 4096 + dst;
        gload_lds16(Kh + ko,  KhS + cb);
        gload_lds16(Kl + ko,  KlS + cb);
        gload_lds16(Vth + vo, VhS + cb);
        gload_lds16(Vtl + vo, VlS + cb);
    };

    const int NT = SEQ / 64;
    stage(0, 0);
    __syncthreads();   // drain tile-0 DMA

    for (int kt = 0; kt < NT; ++kt) {
        const int c = kt & 1;
        if (kt + 1 < NT) stage(kt + 1, c ^ 1);   // async loads overlap compute
        const int cb = c * 4096;

        // ---- scores: 3-term split MFMA ----
        f32x4 s[2][4] = {};
        __builtin_amdgcn_s_setprio(1);
        #pragma unroll
        for (int kst = 0; kst < 2; ++kst) {
            #pragma unroll
            for (int ni = 0; ni < 4; ++ni) {
                int off = cb + swzE(ni * 16 + l15, kst * 32 + g * 8);
                bf16x8 kh_ = *(const bf16x8*)&KhS[off];
                bf16x8 kl_ = *(const bf16x8*)&KlS[off];
                #pragma unroll
                for (int mi = 0; mi < 2; ++mi) {
                    s[mi][ni] = mfma16(qh[mi][kst], kh_, s[mi][ni]);
                    s[mi][ni] = mfma16(ql[mi][kst], kh_, s[mi][ni]);
                    s[mi][ni] = mfma16(qh[mi][kst], kl_, s[mi][ni]);
                }
            }
        }
        __builtin_amdgcn_s_setprio(0);

        // ---- online softmax (exp2 domain), fast path ----
        #pragma unroll
        for (int mi = 0; mi < 2; ++mi) {
            #pragma unroll
            for (int r = 0; r < 4; ++r) {
                float mx = fmaxf(fmaxf(s[mi][0][r], s[mi][1][r]),
                                 fmaxf(s[mi][2][r], s[mi][3][r]));
                // local max suffices for the trigger; reduce only if rescaling
                if (__any(mx - m_run[mi][r] > 8.0f)) {
                    #pragma unroll
                    for (int off = 1; off < 16; off <<= 1)
                        mx = fmaxf(mx, __shfl_xor(mx, off));
                    const float mnew  = fmaxf(m_run[mi][r], mx);
                    const float alpha = fexp2(m_run[mi][r] - mnew);
                    #pragma unroll
                    for (int ni = 0; ni < 4; ++ni) o[mi][ni][r] *= alpha;
                    l_run[mi][r] *= alpha;
                    m_run[mi][r] = mnew;
                }
                float p0 = fexp2(s[mi][0][r] - m_run[mi][r]);
                float p1 = fexp2(s[mi][1][r] - m_run[mi][r]);
                float p2 = fexp2(s[mi][2][r] - m_run[mi][r]);
                float p3 = fexp2(s[mi][3][r] - m_run[mi][r]);
                l_run[mi][r] += (p0 + p1) + (p2 + p3);   // per-lane partial

                bf16 h0, l0, h1, l1, h2, l2, h3, l3;
                split2(p0, h0, l0); split2(p1, h1, l1);
                split2(p2, h2, l2); split2(p3, h3, l3);
                const int prow = wq + mi * 16 + g * 4 + r;
                const int e = swzE(prow, l15 * 4);
                *(bf16x4*)&PhS[e] = (bf16x4){h0, h1, h2, h3};
                *(bf16x4*)&PlS[e] = (bf16x4){l0, l1, l2, l3};
            }
        }
        // P rows are wave-private: no barrier needed.

        // ---- O += P @ V (3-term split) ----
        __builtin_amdgcn_s_setprio(1);
        #pragma unroll
        for (int kst = 0; kst < 2; ++kst) {
            bf16x8 ph[2], pl[2];
            #pragma unroll
            for (int mi = 0; mi < 2; ++mi) {
                int poff = swzE(wq + mi * 16 + l15, kst * 32 + g * 8);
                ph[mi] = *(const bf16x8*)&PhS[poff];
                pl[mi] = *(const bf16x8*)&PlS[poff];
            }
            #pragma unroll
            for (int ni = 0; ni < 4; ++ni) {
                int off = cb + swzE(ni * 16 + l15, kst * 32 + g * 8);
                bf16x8 vh_ = *(const bf16x8*)&VhS[off];
                bf16x8 vl_ = *(const bf16x8*)&VlS[off];
                #pragma unroll
                for (int mi = 0; mi < 2; ++mi) {
                    o[mi][ni] = mfma16(ph[mi], vh_, o[mi][ni]);
                    o[mi][ni] = mfma16(pl[mi], vh_, o[mi][ni]);
                    o[mi][ni] = mfma16(ph[mi], vl_, o[mi][ni]);
                }
            }
        }
        __builtin_amdgcn_s_setprio(0);

        __syncthreads();   // drains next-tile DMA; fences buffer reuse
    }

    // ---- epilogue: reduce deferred l partials, normalize, store ----
    #pragma unroll
    for (int mi = 0; mi < 2; ++mi)
        #pragma unroll
        for (int r = 0; r < 4; ++r) {
            float l = l_run[mi][r];
            #pragma unroll
            for (int off = 1; off < 16; off <<= 1)
                l += __shfl_xor(l, off);
            const float inv = 1.0f / l;
            const int row = q0 + wq + mi * 16 + g * 4 + r;
            #pragma unroll
            for (int ni = 0; ni < 4; ++ni)
                att[(size_t)(b * SEQ + row) * DM + h * DK + ni * 16 + l15] =
                    o[mi][ni][r] * inv;
        }
}

// ---------------------------------------------------------------------------
extern "C" void kernel_launch(void* const* d_in, const int* in_sizes, int n_in,
                              void* d_out, int out_size, void* d_ws, size_t ws_size,
                              hipStream_t stream) {
    const float* x    = (const float*)d_in[0];
    const float* Wqkv = (const float*)d_in[1];
    const float* Wout = (const float*)d_in[2];
    float* out = (float*)d_out;

    char* ws = (char*)d_ws;
    float* qkv  = (float*)(ws);                          // 48 MB
    float* attn = (float*)(ws + (size_t)48 * 1048576);   // 16 MB
    bf16* Khp  = (bf16*)(ws + (size_t)64 * 1048576);     // 8 MB
    bf16* Klp  = (bf16*)(ws + (size_t)72 * 1048576);     // 8 MB
    bf16* Vthp = (bf16*)(ws + (size_t)80 * 1048576);     // 8 MB
    bf16* Vtlp = (bf16*)(ws + (size_t)88 * 1048576);     // 8 MB
    bf16* Wqh  = (bf16*)(ws + (size_t)96 * 1048576);     // 1.5 MB
    bf16* Wql  = (bf16*)(ws + (size_t)98 * 1048576);
    bf16* Woh  = (bf16*)(ws + (size_t)100 * 1048576);    // 0.5 MB
    bf16* Wol  = (bf16*)(ws + (size_t)101 * 1048576);

    const int M = NB * SEQ;   // 8192
    const int FLASH_LDS = 131072;   // 128 KB dynamic LDS

    hipFuncSetAttribute((const void*)flash_mfma,
                        hipFuncAttributeMaxDynamicSharedMemorySize, FLASH_LDS);

    prep_w<<<dim3(DM / 64, (3 * DM) / 64), 256, 0, stream>>>(Wqkv, Wqh, Wql, DM, 3 * DM);
    prep_w<<<dim3(DM / 64, DM / 64), 256, 0, stream>>>(Wout, Woh, Wol, DM, DM);

    gemm_split<<<dim3((3 * DM) / 128, M / 128), 256, 0, stream>>>(
        x, Wqh, Wql, qkv, M, 3 * DM, DM);

    convert_kv<<<dim3(SEQ / 64, NH, NB), 256, 0, stream>>>(qkv, Khp, Klp, Vthp, Vtlp);

    flash_mfma<<<dim3((SEQ / 256) * NH * NB), 512, FLASH_LDS, stream>>>(
        qkv, Khp, Klp, Vthp, Vtlp, attn);

    gemm_split<<<dim3(DM / 128, M / 128), 256, 0, stream>>>(
        attn, Woh, Wol, out, M, DM, DM);
}

// Round 10
// 243.620 us; speedup vs baseline: 1.8842x; 1.1877x over previous
//
#include <hip/hip_runtime.h>
#include <hip/hip_bf16.h>

#define SEQ 4096
#define NB 2
#define DM 512
#define NH 8
#define DK 64

typedef __bf16 bf16;
typedef __bf16 bf16x4 __attribute__((ext_vector_type(4)));
typedef __bf16 bf16x8 __attribute__((ext_vector_type(8)));
typedef float  f32x4 __attribute__((ext_vector_type(4)));

__device__ __forceinline__ f32x4 mfma16(bf16x8 a, bf16x8 b, f32x4 c) {
    return __builtin_amdgcn_mfma_f32_16x16x32_bf16(a, b, c, 0, 0, 0);
}

__device__ __forceinline__ float fexp2(float x) {
    return __builtin_amdgcn_exp2f(x);   // raw v_exp_f32 (2^x)
}

// Async global->LDS, 16B per lane. LDS dest is wave-uniform base + lane*16.
__device__ __forceinline__ void gload_lds16(const bf16* g, bf16* l) {
    __builtin_amdgcn_global_load_lds(
        (const __attribute__((address_space(1))) void*)g,
        (__attribute__((address_space(3))) void*)l, 16, 0, 0);
}

// LDS rows are 64 bf16 (128 B). XOR-swizzle 16B slot by row (G4 fix).
__device__ __forceinline__ int swzE(int row, int e) {
    return row * 64 + (e ^ ((row & 7) << 3));
}

__device__ __forceinline__ void split2(float f, bf16& h, bf16& l) {
    bf16 hh = (bf16)f;
    h = hh;
    l = (bf16)(f - (float)hh);
}

// Load 8 contiguous fp32, scale, split into hi/lo bf16x8.
__device__ __forceinline__ void split8(const float* __restrict__ p, float scale,
                                       bf16x8& h, bf16x8& l) {
    const float4 v0 = *(const float4*)p;
    const float4 v1 = *(const float4*)(p + 4);
    float f0 = v0.x * scale, f1 = v0.y * scale, f2 = v0.z * scale, f3 = v0.w * scale;
    float f4 = v1.x * scale, f5 = v1.y * scale, f6 = v1.z * scale, f7 = v1.w * scale;
    bf16 h0 = (bf16)f0, h1 = (bf16)f1, h2 = (bf16)f2, h3 = (bf16)f3;
    bf16 h4 = (bf16)f4, h5 = (bf16)f5, h6 = (bf16)f6, h7 = (bf16)f7;
    h = (bf16x8){h0, h1, h2, h3, h4, h5, h6, h7};
    l = (bf16x8){(bf16)(f0 - (float)h0), (bf16)(f1 - (float)h1),
                 (bf16)(f2 - (float)h2), (bf16)(f3 - (float)h3),
                 (bf16)(f4 - (float)h4), (bf16)(f5 - (float)h5),
                 (bf16)(f6 - (float)h6), (bf16)(f7 - (float)h7)};
}

// ---------------------------------------------------------------------------
// Transpose + split weights: W[K][N] fp32 -> Wt_hi/lo[N][K] bf16.
// ---------------------------------------------------------------------------
__global__ __launch_bounds__(256)
void prep_w(const float* __restrict__ W, bf16* __restrict__ Wth,
            bf16* __restrict__ Wtl, int K, int N) {
    __shared__ float T[64][65];
    const int k0 = blockIdx.x * 64, n0 = blockIdx.y * 64;
    const int t = threadIdx.x;
    #pragma unroll
    for (int i = 0; i < 4; ++i) {
        int r = i * 16 + (t >> 4);
        int c = (t & 15) * 4;
        float4 v = *(const float4*)&W[(size_t)(k0 + r) * N + n0 + c];
        T[r][c + 0] = v.x; T[r][c + 1] = v.y; T[r][c + 2] = v.z; T[r][c + 3] = v.w;
    }
    __syncthreads();
    #pragma unroll
    for (int i = 0; i < 4; ++i) {
        int n = i * 16 + (t >> 4);
        int c = (t & 15) * 4;
        float a0 = T[c + 0][n], a1 = T[c + 1][n], a2 = T[c + 2][n], a3 = T[c + 3][n];
        bf16 h0 = (bf16)a0, h1 = (bf16)a1, h2 = (bf16)a2, h3 = (bf16)a3;
        bf16x4 hv = (bf16x4){h0, h1, h2, h3};
        bf16x4 lv = (bf16x4){(bf16)(a0 - (float)h0), (bf16)(a1 - (float)h1),
                             (bf16)(a2 - (float)h2), (bf16)(a3 - (float)h3)};
        *(bf16x4*)&Wth[(size_t)(n0 + n) * K + k0 + c] = hv;
        *(bf16x4*)&Wtl[(size_t)(n0 + n) * K + k0 + c] = lv;
    }
}

// ---------------------------------------------------------------------------
// Split-bf16 MFMA GEMM: C[M,N] fp32 = A[M,K] fp32 @ Bt[N,K]^T (pre-split bf16).
// 128x128 tile, BK=64, 4 waves of 64x64 (4x4 16x16x32 frags), 3-term split.
// ---------------------------------------------------------------------------
__global__ __launch_bounds__(256, 2)
void gemm_split(const float* __restrict__ A, const bf16* __restrict__ Bth,
                const bf16* __restrict__ Btl, float* __restrict__ C,
                int M, int N, int K) {
    __shared__ bf16 Ah[128 * 64], Al[128 * 64], Bh[128 * 64], Bl[128 * 64];
    const int t = threadIdx.x;
    const int lane = t & 63, w = t >> 6;
    const int l15 = lane & 15, g = lane >> 4;
    const int wm = (w >> 1) * 64, wn = (w & 1) * 64;
    const int rowA = blockIdx.y * 128;
    const int colB = blockIdx.x * 128;
    const int sr = t >> 1;          // staging row 0..127
    const int sc = (t & 1) * 32;    // staging k-chunk

    f32x4 acc[4][4] = {};

    for (int k0 = 0; k0 < K; k0 += 64) {
        __syncthreads();
        #pragma unroll
        for (int u = 0; u < 4; ++u) {   // A: fp32 -> hi/lo
            bf16x8 h, l;
            split8(&A[(size_t)(rowA + sr) * K + k0 + sc + u * 8], 1.0f, h, l);
            int off = swzE(sr, sc + u * 8);
            *(bf16x8*)&Ah[off] = h;
            *(bf16x8*)&Al[off] = l;
        }
        #pragma unroll
        for (int u = 0; u < 4; ++u) {   // B: pre-split copy
            int off = swzE(sr, sc + u * 8);
            *(bf16x8*)&Bh[off] = *(const bf16x8*)&Bth[(size_t)(colB + sr) * K + k0 + sc + u * 8];
            *(bf16x8*)&Bl[off] = *(const bf16x8*)&Btl[(size_t)(colB + sr) * K + k0 + sc + u * 8];
        }
        __syncthreads();
        #pragma unroll
        for (int kst = 0; kst < 2; ++kst) {
            bf16x8 ah[4], al[4];
            #pragma unroll
            for (int mi = 0; mi < 4; ++mi) {
                int off = swzE(wm + mi * 16 + l15, kst * 32 + g * 8);
                ah[mi] = *(const bf16x8*)&Ah[off];
                al[mi] = *(const bf16x8*)&Al[off];
            }
            #pragma unroll
            for (int ni = 0; ni < 4; ++ni) {
                int off = swzE(wn + ni * 16 + l15, kst * 32 + g * 8);
                bf16x8 bh = *(const bf16x8*)&Bh[off];
                bf16x8 bl = *(const bf16x8*)&Bl[off];
                #pragma unroll
                for (int mi = 0; mi < 4; ++mi) {
                    acc[mi][ni] = mfma16(ah[mi], bh, acc[mi][ni]);
                    acc[mi][ni] = mfma16(ah[mi], bl, acc[mi][ni]);
                    acc[mi][ni] = mfma16(al[mi], bh, acc[mi][ni]);
                }
            }
        }
    }
    #pragma unroll
    for (int mi = 0; mi < 4; ++mi)
        #pragma unroll
        for (int ni = 0; ni < 4; ++ni)
            #pragma unroll
            for (int r = 0; r < 4; ++r) {
                int row = rowA + wm + mi * 16 + g * 4 + r;
                int col = colB + wn + ni * 16 + l15;
                C[(size_t)row * N + col] = acc[mi][ni][r];
            }
}

// ---------------------------------------------------------------------------
// Convert K,V from fp32 qkv to split bf16. K: [bh][s][d] hi/lo. V: transposed
// AND slot-permuted [bh][d][slot], slot = (s&15)*4 + ((s>>4)&3) within each
// 64-block — the same permutation the flash kernel uses for P, so PV matches.
// V is hi-only (PV is 1-term; V-lo RMS contribution ~1e-5, see R9/R10 notes).
// ---------------------------------------------------------------------------
__global__ __launch_bounds__(256)
void convert_kv(const float* __restrict__ qkv,
                bf16* __restrict__ Kh, bf16* __restrict__ Kl,
                bf16* __restrict__ Vth) {
    const int st = blockIdx.x, h = blockIdx.y, b = blockIdx.z;
    const int bh = b * NH + h;
    __shared__ float VT[64][68];
    const int t = threadIdx.x;
    const int r = t >> 2, c16 = (t & 3) * 16;

    // K rows
    const size_t kbase = ((size_t)(b * SEQ + st * 64 + r) * 3 + 1) * DM + h * DK;
    #pragma unroll
    for (int u = 0; u < 2; ++u) {
        bf16x8 hh, ll;
        split8(&qkv[kbase + c16 + u * 8], 1.0f, hh, ll);
        size_t o = ((size_t)bh * SEQ + st * 64 + r) * DK + c16 + u * 8;
        *(bf16x8*)&Kh[o] = hh;
        *(bf16x8*)&Kl[o] = ll;
    }
    // V -> LDS fp32
    const size_t vbase = ((size_t)(b * SEQ + st * 64 + r) * 3 + 2) * DM + h * DK;
    #pragma unroll
    for (int u = 0; u < 4; ++u) {
        float4 v = *(const float4*)&qkv[vbase + c16 + u * 4];
        VT[r][c16 + u * 4 + 0] = v.x; VT[r][c16 + u * 4 + 1] = v.y;
        VT[r][c16 + u * 4 + 2] = v.z; VT[r][c16 + u * 4 + 3] = v.w;
    }
    __syncthreads();
    // transposed + permuted write: thread owns d=r, slots c16..c16+15
    bf16x8 vh0{}, vh1{};
    #pragma unroll
    for (int i = 0; i < 8; ++i) {
        int slot = c16 + i;
        vh0[i] = (bf16)VT[(slot & 3) * 16 + (slot >> 2)][r];
    }
    #pragma unroll
    for (int i = 0; i < 8; ++i) {
        int slot = c16 + 8 + i;
        vh1[i] = (bf16)VT[(slot & 3) * 16 + (slot >> 2)][r];
    }
    size_t vo = ((size_t)bh * DK + r) * SEQ + st * 64 + c16;
    *(bf16x8*)&Vth[vo] = vh0;
    *(bf16x8*)&Vth[vo + 8] = vh1;
}

// ---------------------------------------------------------------------------
// MFMA flash attention, R10 = R9 design with the LDS size bug fixed.
// 128 q-rows/block (8 waves x 16 rows), grid 512 -> 2 blocks/CU at 64 KB LDS
// (R9 FAILED because FLASH_LDS was 56 KB but KhS+KlS+VhS+PhS = 16K*4 = 64 KB:
// PhS rows >= 64 wrote out of bounds, corrupting K tiles). PV single-term.
// 2-phase dbuf + gload_lds + fast-path softmax + setprio (R7/R8 validated).
// ---------------------------------------------------------------------------
__global__ __launch_bounds__(512)
void flash_mfma(const float* __restrict__ qkv,
                const bf16* __restrict__ Kh, const bf16* __restrict__ Kl,
                const bf16* __restrict__ Vth,
                float* __restrict__ att) {
    extern __shared__ bf16 smem[];
    bf16* KhS = smem;              // [2][64*64] dbuf, 16 KB
    bf16* KlS = smem + 8192;       // 16 KB
    bf16* VhS = smem + 16384;      // 16 KB
    bf16* PhS = smem + 24576;      // [128*64], 16 KB  -> total 64 KB

    // XCD-bijective swizzle: nwg = 512 (divisible by 8).
    const int nwg = (int)gridDim.x;
    const int cpx = nwg >> 3;
    const int bid = (int)blockIdx.x;
    const int wg = (bid & 7) * cpx + (bid >> 3);
    const int qt = wg & 31;        // 32 q-tiles of 128 rows
    const int bh = wg >> 5;
    const int h = bh & 7, b = bh >> 3;

    const int t = threadIdx.x, lane = t & 63, w = t >> 6;   // 8 waves
    const int l15 = lane & 15, g = lane >> 4;
    const int q0 = qt * 128;
    const int wq = w * 16;   // each wave owns 16 q-rows

    const float LOG2E = 1.44269504088896f;

    // Q fragments in registers (scaled by log2e/8, split hi/lo)
    bf16x8 qh[2], ql[2];
    {
        const int row = q0 + wq + l15;
        const size_t base = ((size_t)(b * SEQ + row) * 3 + 0) * DM + h * DK + g * 8;
        split8(&qkv[base], 0.125f * LOG2E, qh[0], ql[0]);
        split8(&qkv[base + 32], 0.125f * LOG2E, qh[1], ql[1]);
    }

    float m_run[4], l_run[4];
    f32x4 o[4] = {};
    #pragma unroll
    for (int r = 0; r < 4; ++r) { m_run[r] = -1e30f; l_run[r] = 0.f; }

    // Staging: LDS dest = wave base + lane*16B (global_load_lds pattern);
    // global source column pre-swizzled (G21 both-sides rule).
    const int sr = t >> 3;
    const int sc8 = (t & 7) * 8;
    const int scs = sc8 ^ ((sr & 7) << 3);
    const size_t kgo = ((size_t)bh * SEQ + sr) * DK + scs;
    const size_t vgo = ((size_t)bh * DK + sr) * SEQ + scs;
    const int dst = t * 8;   // element offset within a [64*64] buffer

    auto stage = [&](int kt, int c) {
        const size_t ko = kgo + (size_t)kt * 64 * DK;
        const size_t vo = vgo + (size_t)kt * 64;
        const int cb = c * 4096 + dst;
        gload_lds16(Kh + ko,  KhS + cb);
        gload_lds16(Kl + ko,  KlS + cb);
        gload_lds16(Vth + vo, VhS + cb);
    };

    const int NT = SEQ / 64;
    stage(0, 0);
    __syncthreads();   // drain tile-0 DMA

    for (int kt = 0; kt < NT; ++kt) {
        const int c = kt & 1;
        if (kt + 1 < NT) stage(kt + 1, c ^ 1);   // async loads overlap compute
        const int cb = c * 4096;

        // ---- scores: 3-term split MFMA ----
        f32x4 s[4] = {};
        __builtin_amdgcn_s_setprio(1);
        #pragma unroll
        for (int kst = 0; kst < 2; ++kst) {
            #pragma unroll
            for (int ni = 0; ni < 4; ++ni) {
                int off = cb + swzE(ni * 16 + l15, kst * 32 + g * 8);
                bf16x8 kh_ = *(const bf16x8*)&KhS[off];
                bf16x8 kl_ = *(const bf16x8*)&KlS[off];
                s[ni] = mfma16(qh[kst], kh_, s[ni]);
                s[ni] = mfma16(ql[kst], kh_, s[ni]);
                s[ni] = mfma16(qh[kst], kl_, s[ni]);
            }
        }
        __builtin_amdgcn_s_setprio(0);

        // ---- online softmax (exp2 domain), fast path ----
        #pragma unroll
        for (int r = 0; r < 4; ++r) {
            float mx = fmaxf(fmaxf(s[0][r], s[1][r]), fmaxf(s[2][r], s[3][r]));
            // local max suffices for the trigger; reduce only if rescaling
            if (__any(mx - m_run[r] > 8.0f)) {
                #pragma unroll
                for (int off = 1; off < 16; off <<= 1)
                    mx = fmaxf(mx, __shfl_xor(mx, off));
                const float mnew  = fmaxf(m_run[r], mx);
                const float alpha = fexp2(m_run[r] - mnew);
                #pragma unroll
                for (int ni = 0; ni < 4; ++ni) o[ni][r] *= alpha;
                l_run[r] *= alpha;
                m_run[r] = mnew;
            }
            float p0 = fexp2(s[0][r] - m_run[r]);
            float p1 = fexp2(s[1][r] - m_run[r]);
            float p2 = fexp2(s[2][r] - m_run[r]);
            float p3 = fexp2(s[3][r] - m_run[r]);
            l_run[r] += (p0 + p1) + (p2 + p3);   // per-lane partial

            const int prow = wq + g * 4 + r;
            const int e = swzE(prow, l15 * 4);
            *(bf16x4*)&PhS[e] = (bf16x4){(bf16)p0, (bf16)p1, (bf16)p2, (bf16)p3};
        }
        // P rows are wave-private: no barrier needed.

        // ---- O += P @ V (single term) ----
        __builtin_amdgcn_s_setprio(1);
        #pragma unroll
        for (int kst = 0; kst < 2; ++kst) {
            const int poff = swzE(wq + l15, kst * 32 + g * 8);
            bf16x8 ph = *(const bf16x8*)&PhS[poff];
            #pragma unroll
            for (int ni = 0; ni < 4; ++ni) {
                int off = cb + swzE(ni * 16 + l15, kst * 32 + g * 8);
                bf16x8 vh_ = *(const bf16x8*)&VhS[off];
                o[ni] = mfma16(ph, vh_, o[ni]);
            }
        }
        __builtin_amdgcn_s_setprio(0);

        __syncthreads();   // drains next-tile DMA; fences buffer reuse
    }

    // ---- epilogue: reduce deferred l partials, normalize, store ----
    #pragma unroll
    for (int r = 0; r < 4; ++r) {
        float l = l_run[r];
        #pragma unroll
        for (int off = 1; off < 16; off <<= 1)
            l += __shfl_xor(l, off);
        const float inv = 1.0f / l;
        const int row = q0 + wq + g * 4 + r;
        #pragma unroll
        for (int ni = 0; ni < 4; ++ni)
            att[(size_t)(b * SEQ + row) * DM + h * DK + ni * 16 + l15] =
                o[ni][r] * inv;
    }
}

// ---------------------------------------------------------------------------
extern "C" void kernel_launch(void* const* d_in, const int* in_sizes, int n_in,
                              void* d_out, int out_size, void* d_ws, size_t ws_size,
                              hipStream_t stream) {
    const float* x    = (const float*)d_in[0];
    const float* Wqkv = (const float*)d_in[1];
    const float* Wout = (const float*)d_in[2];
    float* out = (float*)d_out;

    char* ws = (char*)d_ws;
    float* qkv  = (float*)(ws);                          // 48 MB
    float* attn = (float*)(ws + (size_t)48 * 1048576);   // 16 MB
    bf16* Khp  = (bf16*)(ws + (size_t)64 * 1048576);     // 8 MB
    bf16* Klp  = (bf16*)(ws + (size_t)72 * 1048576);     // 8 MB
    bf16* Vthp = (bf16*)(ws + (size_t)80 * 1048576);     // 8 MB
    bf16* Wqh  = (bf16*)(ws + (size_t)96 * 1048576);     // 1.5 MB
    bf16* Wql  = (bf16*)(ws + (size_t)98 * 1048576);
    bf16* Woh  = (bf16*)(ws + (size_t)100 * 1048576);    // 0.5 MB
    bf16* Wol  = (bf16*)(ws + (size_t)101 * 1048576);

    const int M = NB * SEQ;   // 8192
    const int FLASH_LDS = 65536;   // 64 KB: KhS+KlS+VhS (dbuf) + PhS, 16K each

    hipFuncSetAttribute((const void*)flash_mfma,
                        hipFuncAttributeMaxDynamicSharedMemorySize, FLASH_LDS);

    prep_w<<<dim3(DM / 64, (3 * DM) / 64), 256, 0, stream>>>(Wqkv, Wqh, Wql, DM, 3 * DM);
    prep_w<<<dim3(DM / 64, DM / 64), 256, 0, stream>>>(Wout, Woh, Wol, DM, DM);

    gemm_split<<<dim3((3 * DM) / 128, M / 128), 256, 0, stream>>>(
        x, Wqh, Wql, qkv, M, 3 * DM, DM);

    convert_kv<<<dim3(SEQ / 64, NH, NB), 256, 0, stream>>>(qkv, Khp, Klp, Vthp);

    flash_mfma<<<dim3((SEQ / 128) * NH * NB), 512, FLASH_LDS, stream>>>(
        qkv, Khp, Klp, Vthp, attn);

    gemm_split<<<dim3(DM / 128, M / 128), 256, 0, stream>>>(
        attn, Woh, Wol, out, M, DM, DM);
}